// Round 5
// baseline (193.143 us; speedup 1.0000x reference)
//
#include <hip/hip_runtime.h>
#include <math.h>

#define BB 8
#define NN 2048
#define FF 128
#define CH 128        // chunks per batch
#define CHSZ 16       // NN / CH

typedef __attribute__((ext_vector_type(8))) short short8;
typedef __attribute__((ext_vector_type(4))) float f32x4;

__device__ __forceinline__ ushort f2bf(float x) {
    uint u = __float_as_uint(x);
    uint r = (u + 0x7FFFu + ((u >> 16) & 1u)) >> 16;   // round-nearest-even
    return (ushort)r;
}
__device__ __forceinline__ float bf2f(ushort x) {
    return __uint_as_float(((uint)x) << 16);
}

// ---------------------------------------------------------------------------
// Kernel 1 (MFMA, verified round 4): Wh = h @ W^T via bf16 hi/lo split.
// 256 thr = 4 waves, 64 rows/block. C/D layout m89-verified.
// ---------------------------------------------------------------------------
__global__ __launch_bounds__(256) void k1_wh(
        const float* __restrict__ h, const float* __restrict__ W,
        const float* __restrict__ a, float* __restrict__ Wh,
        float* __restrict__ s1, float* __restrict__ s2) {
    __shared__ __align__(16) ushort Whi[128][136];
    __shared__ __align__(16) ushort Wlo[128][136];
    __shared__ __align__(16) ushort hhi[64][136];
    __shared__ __align__(16) ushort hlo[64][136];
    const int tid = threadIdx.x;
    const int row0 = blockIdx.x * 64;

    for (int i = tid; i < 4096; i += 256) {
        int g = i >> 5, k4 = (i & 31) * 4;
        float4 wv = *(const float4*)&W[g * 128 + k4];
        ushort h0 = f2bf(wv.x), h1 = f2bf(wv.y), h2 = f2bf(wv.z), h3 = f2bf(wv.w);
        ushort l0 = f2bf(wv.x - bf2f(h0)), l1 = f2bf(wv.y - bf2f(h1));
        ushort l2 = f2bf(wv.z - bf2f(h2)), l3 = f2bf(wv.w - bf2f(h3));
        uint2 hw, lw;
        hw.x = (uint)h0 | ((uint)h1 << 16); hw.y = (uint)h2 | ((uint)h3 << 16);
        lw.x = (uint)l0 | ((uint)l1 << 16); lw.y = (uint)l2 | ((uint)l3 << 16);
        *(uint2*)&Whi[g][k4] = hw;
        *(uint2*)&Wlo[g][k4] = lw;
    }
    for (int i = tid; i < 2048; i += 256) {
        int r = i >> 5, k4 = (i & 31) * 4;
        float4 hv = *(const float4*)&h[(row0 + r) * 128 + k4];
        ushort h0 = f2bf(hv.x), h1 = f2bf(hv.y), h2 = f2bf(hv.z), h3 = f2bf(hv.w);
        ushort l0 = f2bf(hv.x - bf2f(h0)), l1 = f2bf(hv.y - bf2f(h1));
        ushort l2 = f2bf(hv.z - bf2f(h2)), l3 = f2bf(hv.w - bf2f(h3));
        uint2 hw, lw;
        hw.x = (uint)h0 | ((uint)h1 << 16); hw.y = (uint)h2 | ((uint)h3 << 16);
        lw.x = (uint)l0 | ((uint)l1 << 16); lw.y = (uint)l2 | ((uint)l3 << 16);
        *(uint2*)&hhi[r][k4] = hw;
        *(uint2*)&hlo[r][k4] = lw;
    }
    __syncthreads();

    const int lane = tid & 63;
    const int wid = tid >> 6;
    const int gl = lane & 15;
    const int kg = lane >> 4;
    const int lr = wid * 16 + gl;

    f32x4 acc[8];
#pragma unroll
    for (int gt = 0; gt < 8; ++gt) acc[gt] = (f32x4){0.f, 0.f, 0.f, 0.f};

#pragma unroll
    for (int t = 0; t < 4; ++t) {
        const int k0 = t * 32 + kg * 8;
        short8 ah = *(const short8*)&hhi[lr][k0];
        short8 al = *(const short8*)&hlo[lr][k0];
#pragma unroll
        for (int gt = 0; gt < 8; ++gt) {
            const int g = gt * 16 + gl;
            short8 bh = *(const short8*)&Whi[g][k0];
            short8 bl = *(const short8*)&Wlo[g][k0];
            acc[gt] = __builtin_amdgcn_mfma_f32_16x16x32_bf16(ah, bh, acc[gt], 0, 0, 0);
            acc[gt] = __builtin_amdgcn_mfma_f32_16x16x32_bf16(ah, bl, acc[gt], 0, 0, 0);
            acc[gt] = __builtin_amdgcn_mfma_f32_16x16x32_bf16(al, bh, acc[gt], 0, 0, 0);
        }
    }

    float p1a[4] = {0.f, 0.f, 0.f, 0.f}, p2a[4] = {0.f, 0.f, 0.f, 0.f};
#pragma unroll
    for (int gt = 0; gt < 8; ++gt) {
        const int g = gt * 16 + gl;
        const float a1v = a[g];
        const float a2v = a[128 + g];
#pragma unroll
        for (int r = 0; r < 4; ++r) {
            float wvv = acc[gt][r];
            Wh[(row0 + wid * 16 + kg * 4 + r) * 128 + g] = wvv;
            p1a[r] += wvv * a1v;
            p2a[r] += wvv * a2v;
        }
    }
#pragma unroll
    for (int s = 1; s < 16; s <<= 1) {
#pragma unroll
        for (int r = 0; r < 4; ++r) {
            p1a[r] += __shfl_xor(p1a[r], s, 64);
            p2a[r] += __shfl_xor(p2a[r], s, 64);
        }
    }
    if (gl == 0) {
#pragma unroll
        for (int r = 0; r < 4; ++r) {
            int row = row0 + wid * 16 + kg * 4 + r;
            s1[row] = p1a[r];
            s2[row] = p2a[r];
        }
    }
}

// ---------------------------------------------------------------------------
// Kernel 2 (verified): stable rank by s2 + exp + threshold count.
// grid = B*32, block = 512. 8 waves each scan 256 keys.
// ---------------------------------------------------------------------------
__global__ __launch_bounds__(512) void k2_rank(
        const float* __restrict__ s2, const float* __restrict__ s1,
        int* __restrict__ idxs, float* __restrict__ ps,
        int* __restrict__ lo_arr) {
    __shared__ __align__(16) float ls[NN];
    __shared__ int part[8][64];
    __shared__ int lpart[8][64];
    __shared__ float wmax[8];
    const int t = threadIdx.x;
    const int blk = blockIdx.x;
    const int b = blk >> 5;
    const int seg = blk & 31;
    const int base = b * NN;
    float4* ls4 = (float4*)ls;
    const float4* g4 = (const float4*)(s2 + base);
    float m;
    {
        float4 v4 = g4[t];
        ls4[t] = v4;
        m = fmaxf(fmaxf(v4.x, v4.y), fmaxf(v4.z, v4.w));
    }
#pragma unroll
    for (int s = 1; s < 64; s <<= 1) m = fmaxf(m, __shfl_xor(m, s, 64));
    if ((t & 63) == 0) wmax[t >> 6] = m;
    __syncthreads();
    float M = wmax[0];
#pragma unroll
    for (int i = 1; i < 8; ++i) M = fmaxf(M, wmax[i]);
    const int jj = t & 63;
    const int w  = t >> 6;
    const int j  = seg * 64 + jj;
    const float v = ls[j];
    const float s1v = s1[base + j];
    int rank = 0, cnt = 0;
#pragma unroll 8
    for (int q = 0; q < 64; ++q) {
        float4 kv = ls4[w * 64 + q];
        int kg = w * 256 + q * 4;
        rank += (kv.x < v) | ((kv.x == v) & (kg + 0 < j));
        rank += (kv.y < v) | ((kv.y == v) & (kg + 1 < j));
        rank += (kv.z < v) | ((kv.z == v) & (kg + 2 < j));
        rank += (kv.w < v) | ((kv.w == v) & (kg + 3 < j));
        cnt += (s1v + kv.x <= 0.f);
        cnt += (s1v + kv.y <= 0.f);
        cnt += (s1v + kv.z <= 0.f);
        cnt += (s1v + kv.w <= 0.f);
    }
    part[w][jj] = rank;
    lpart[w][jj] = cnt;
    __syncthreads();
    if (t < 64) {
        int r = 0, lo = 0;
#pragma unroll
        for (int ww = 0; ww < 8; ++ww) {
            r  += part[ww][t];
            lo += lpart[ww][t];
        }
        int jg = seg * 64 + t;
        float vv = ls[jg];
        idxs[base + r] = jg;
        ps[base + r] = expf(vv - M);
        lo_arr[base + jg] = lo;
    }
}

// ---------------------------------------------------------------------------
// Kernel 34 (MERGED k3 + k4): grid = B*32 x 512 thr. No partial/psuf/chunk
// arrays — each block recomputes the batch's 128 chunk totals itself
// (Wh batch tile = 1 MB, L2-hot; 32x redundancy rides the 34 TB/s L2)
// and the within-chunk suffix at lo via a <=16-row gather per output row.
// Summation orders preserved from the verified round-4 pipeline:
//   chunk totals & per-row pp: descending t (15 -> lo) like k3;
//   chunk suffix: register-serial 32 + segment offsets like k4 v2;
//   lp suffix: wave-0 shuffle scan, identical;
//   mean: direct sum of Wh rows (order-insensitive, tolerance-level).
// ---------------------------------------------------------------------------
__global__ __launch_bounds__(512) void k34(
        const float* __restrict__ Wh, const int* __restrict__ idxs,
        const float* __restrict__ ps, const int* __restrict__ lo_arr,
        float* __restrict__ out) {
    __shared__ __align__(16) float cs[CH][132];   // 67.6 KB chunk totals -> suffix
    __shared__ float lp[CH];                      // chunk p totals -> suffix
    __shared__ float mvp[8][128];
    __shared__ float mv[128];
    __shared__ float segt[4][128];
    __shared__ __align__(16) int   lidx[NN];      // 8 KB staged idxs
    __shared__ __align__(16) float lps[NN];       // 8 KB staged ps
    const int tid = threadIdx.x;
    const int blk = blockIdx.x;
    const int b = blk >> 5;
    const int base = b * NN;

    // ---- stage idxs/ps for the batch (coalesced, 512 x 16B) ----
    *(int4*)&lidx[tid * 4]  = ((const int4*)(idxs + base))[tid];
    *(float4*)&lps[tid * 4] = ((const float4*)(ps + base))[tid];
    __syncthreads();

    // ---- step 1: chunk totals. wave w owns chunks w*16..w*16+16. ----
    {
        const int lane = tid & 63;
        const int w = tid >> 6;
        const int f2 = lane * 2;
        float ux = 0.f, uy = 0.f;            // unweighted sum (mean)
#pragma unroll 2
        for (int cc = 0; cc < 16; ++cc) {
            const int c = w * 16 + cc;
            float ax = 0.f, ay = 0.f, pacc = 0.f;
#pragma unroll
            for (int t = CHSZ - 1; t >= 0; --t) {     // descending == k3 order
                const int r = c * CHSZ + t;
                const int j = lidx[r];                // LDS broadcast
                const float pv = lps[r];
                float2 wv = *(const float2*)&Wh[(base + j) * 128 + f2];
                ax += pv * wv.x;
                ay += pv * wv.y;
                ux += wv.x;
                uy += wv.y;
                pacc += pv;
            }
            cs[c][f2] = ax;
            cs[c][f2 + 1] = ay;
            if (lane == 0) lp[c] = pacc;
        }
        mvp[w][f2] = ux;
        mvp[w][f2 + 1] = uy;
    }
    __syncthreads();

    // ---- step 2: suffix scans (register-serial 32 / thread + seg offsets) ----
    const int q = tid >> 7;              // 0..3, owns chunks q*32..+32
    const int f = tid & 127;
    float suf[32];
    {
        float acc = 0.f;
#pragma unroll
        for (int i = 31; i >= 0; --i) {
            acc += cs[q * 32 + i][f];
            suf[i] = acc;
        }
        segt[q][f] = acc;
    }
    // lp suffix: wave 0, 2 elems/lane (verified shuffle logic)
    if (tid < 64) {
        float p0 = lp[tid * 2];
        float p1v = lp[tid * 2 + 1];
        float T = p0 + p1v;
#pragma unroll
        for (int s = 1; s < 64; s <<= 1) {
            float t2 = __shfl_down(T, s, 64);
            if (tid + s < 64) T += t2;
        }
        float E = __shfl_down(T, 1, 64);
        if (tid == 63) E = 0.f;
        lp[tid * 2]     = p0 + p1v + E;
        lp[tid * 2 + 1] = p1v + E;
    }
    if (tid < 128) {
        float s = 0.f;
#pragma unroll
        for (int ww = 0; ww < 8; ++ww) s += mvp[ww][tid];
        mv[tid] = s * (1.f / (float)NN);
    }
    __syncthreads();                     // segt visible
    {
        float off = 0.f;
#pragma unroll
        for (int qq = 1; qq < 4; ++qq)
            if (q + qq < 4) off += segt[q + qq][f];
#pragma unroll
        for (int i = 0; i < 32; ++i)
            cs[q * 32 + i][f] = suf[i] + off;   // own cells only
    }
    __syncthreads();
    // cs[c][f] = inclusive suffix; exclusive at c is cs[c+1] (0 if c==127).
    // lp[c]   = inclusive suffix; exclusive at c is lp[c+1].

    // ---- step 3: combine. 64 rows/block via 4 passes of 16 rows. ----
#pragma unroll
    for (int pass = 0; pass < 4; ++pass) {
        const int rowg = blk * 64 + pass * 16 + (tid >> 5);
        const int fq = (tid & 31) * 4;
        const int lo = lo_arr[rowg];
        float4 v;
        if (lo == NN) {
            v = make_float4(mv[fq], mv[fq + 1], mv[fq + 2], mv[fq + 3]);
        } else {
            const int c = lo >> 4;       // / CHSZ
            float4 pp = make_float4(0.f, 0.f, 0.f, 0.f);
            float den_p = 0.f;
            // within-chunk suffix at lo: descending r == k3's partial order
            for (int r = c * CHSZ + CHSZ - 1; r >= lo; --r) {
                const int j = lidx[r];
                const float pv = lps[r];
                float4 wv = *(const float4*)&Wh[(base + j) * 128 + fq];
                pp.x += pv * wv.x;
                pp.y += pv * wv.y;
                pp.z += pv * wv.z;
                pp.w += pv * wv.w;
                den_p += pv;
            }
            float4 csv = make_float4(0.f, 0.f, 0.f, 0.f);
            float lpE = 0.f;
            if (c < CH - 1) {
                csv = *(const float4*)&cs[c + 1][fq];
                lpE = lp[c + 1];
            }
            const float den = den_p + lpE;
            v.x = (pp.x + csv.x) / den;
            v.y = (pp.y + csv.y) / den;
            v.z = (pp.z + csv.z) / den;
            v.w = (pp.w + csv.w) / den;
        }
        v.x = (v.x > 0.f) ? v.x : expm1f(v.x);
        v.y = (v.y > 0.f) ? v.y : expm1f(v.y);
        v.z = (v.z > 0.f) ? v.z : expm1f(v.z);
        v.w = (v.w > 0.f) ? v.w : expm1f(v.w);
        *(float4*)&out[rowg * 128 + fq] = v;
    }
}

// ---------------------------------------------------------------------------
extern "C" void kernel_launch(void* const* d_in, const int* in_sizes, int n_in,
                              void* d_out, int out_size, void* d_ws, size_t ws_size,
                              hipStream_t stream) {
    (void)in_sizes; (void)n_in; (void)out_size; (void)ws_size;
    const float* h = (const float*)d_in[0];
    const float* W = (const float*)d_in[1];
    const float* a = (const float*)d_in[2];
    // d_in[3]=A1, d_in[4]=A2: dead code in the reference -> never read.
    float* out = (float*)d_out;

    float* Wh     = (float*)d_ws;            // B*N*F = 2,097,152
    float* s1     = Wh + 2097152;            // 16384
    float* s2     = s1 + 16384;
    float* ps     = s2 + 16384;              // 16384
    int*   idxs   = (int*)(ps + 16384);      // 16384 ints
    int*   lo_arr = idxs + 16384;            // 16384 ints

    k1_wh<<<BB * NN / 64, 256, 0, stream>>>(h, W, a, Wh, s1, s2);
    k2_rank<<<BB * 32, 512, 0, stream>>>(s2, s1, idxs, ps, lo_arr);
    k34<<<BB * 32, 512, 0, stream>>>(Wh, idxs, ps, lo_arr, out);
}

// Round 7
// 184.888 us; speedup vs baseline: 1.0446x; 1.0446x over previous
//
#include <hip/hip_runtime.h>
#include <math.h>

#define BB 8
#define NN 2048
#define FF 128
#define CH 128        // chunks per batch
#define CHSZ 16       // NN / CH

typedef __attribute__((ext_vector_type(8))) short short8;
typedef __attribute__((ext_vector_type(4))) float f32x4;

__device__ __forceinline__ ushort f2bf(float x) {
    uint u = __float_as_uint(x);
    uint r = (u + 0x7FFFu + ((u >> 16) & 1u)) >> 16;   // round-nearest-even
    return (ushort)r;
}
__device__ __forceinline__ float bf2f(ushort x) {
    return __uint_as_float(((uint)x) << 16);
}

// ---------------------------------------------------------------------------
// XCD affinity: blockIdx round-robins XCDs (blk%8). Mapping batch = blk&7
// pins all of a batch's blocks (and its Wh/s1/s2/idxs/ps working set, ~1.2 MB
// << 4 MB XCD-L2) to ONE XCD across k1/k2/k34. Pure permutation: perf-only.
// ---------------------------------------------------------------------------

// ---------------------------------------------------------------------------
// Kernel 1 (MFMA, verified round 4): Wh = h @ W^T via bf16 hi/lo split.
// 256 thr = 4 waves, 64 rows/block. C/D layout m89-verified.
// ---------------------------------------------------------------------------
__global__ __launch_bounds__(256) void k1_wh(
        const float* __restrict__ h, const float* __restrict__ W,
        const float* __restrict__ a, float* __restrict__ Wh,
        float* __restrict__ s1, float* __restrict__ s2) {
    __shared__ __align__(16) ushort Whi[128][136];
    __shared__ __align__(16) ushort Wlo[128][136];
    __shared__ __align__(16) ushort hhi[64][136];
    __shared__ __align__(16) ushort hlo[64][136];
    const int tid = threadIdx.x;
    const int blk = blockIdx.x;
    const int bb = blk & 7;              // batch -> XCD affinity
    const int w8 = blk >> 3;             // 0..31 within batch
    const int row0 = (bb * 32 + w8) * 64;

    for (int i = tid; i < 4096; i += 256) {
        int g = i >> 5, k4 = (i & 31) * 4;
        float4 wv = *(const float4*)&W[g * 128 + k4];
        ushort h0 = f2bf(wv.x), h1 = f2bf(wv.y), h2 = f2bf(wv.z), h3 = f2bf(wv.w);
        ushort l0 = f2bf(wv.x - bf2f(h0)), l1 = f2bf(wv.y - bf2f(h1));
        ushort l2 = f2bf(wv.z - bf2f(h2)), l3 = f2bf(wv.w - bf2f(h3));
        uint2 hw, lw;
        hw.x = (uint)h0 | ((uint)h1 << 16); hw.y = (uint)h2 | ((uint)h3 << 16);
        lw.x = (uint)l0 | ((uint)l1 << 16); lw.y = (uint)l2 | ((uint)l3 << 16);
        *(uint2*)&Whi[g][k4] = hw;
        *(uint2*)&Wlo[g][k4] = lw;
    }
    for (int i = tid; i < 2048; i += 256) {
        int r = i >> 5, k4 = (i & 31) * 4;
        float4 hv = *(const float4*)&h[(row0 + r) * 128 + k4];
        ushort h0 = f2bf(hv.x), h1 = f2bf(hv.y), h2 = f2bf(hv.z), h3 = f2bf(hv.w);
        ushort l0 = f2bf(hv.x - bf2f(h0)), l1 = f2bf(hv.y - bf2f(h1));
        ushort l2 = f2bf(hv.z - bf2f(h2)), l3 = f2bf(hv.w - bf2f(h3));
        uint2 hw, lw;
        hw.x = (uint)h0 | ((uint)h1 << 16); hw.y = (uint)h2 | ((uint)h3 << 16);
        lw.x = (uint)l0 | ((uint)l1 << 16); lw.y = (uint)l2 | ((uint)l3 << 16);
        *(uint2*)&hhi[r][k4] = hw;
        *(uint2*)&hlo[r][k4] = lw;
    }
    __syncthreads();

    const int lane = tid & 63;
    const int wid = tid >> 6;
    const int gl = lane & 15;
    const int kg = lane >> 4;
    const int lr = wid * 16 + gl;

    f32x4 acc[8];
#pragma unroll
    for (int gt = 0; gt < 8; ++gt) acc[gt] = (f32x4){0.f, 0.f, 0.f, 0.f};

#pragma unroll
    for (int t = 0; t < 4; ++t) {
        const int k0 = t * 32 + kg * 8;
        short8 ah = *(const short8*)&hhi[lr][k0];
        short8 al = *(const short8*)&hlo[lr][k0];
#pragma unroll
        for (int gt = 0; gt < 8; ++gt) {
            const int g = gt * 16 + gl;
            short8 bh = *(const short8*)&Whi[g][k0];
            short8 bl = *(const short8*)&Wlo[g][k0];
            acc[gt] = __builtin_amdgcn_mfma_f32_16x16x32_bf16(ah, bh, acc[gt], 0, 0, 0);
            acc[gt] = __builtin_amdgcn_mfma_f32_16x16x32_bf16(ah, bl, acc[gt], 0, 0, 0);
            acc[gt] = __builtin_amdgcn_mfma_f32_16x16x32_bf16(al, bh, acc[gt], 0, 0, 0);
        }
    }

    float p1a[4] = {0.f, 0.f, 0.f, 0.f}, p2a[4] = {0.f, 0.f, 0.f, 0.f};
#pragma unroll
    for (int gt = 0; gt < 8; ++gt) {
        const int g = gt * 16 + gl;
        const float a1v = a[g];
        const float a2v = a[128 + g];
#pragma unroll
        for (int r = 0; r < 4; ++r) {
            float wvv = acc[gt][r];
            Wh[(row0 + wid * 16 + kg * 4 + r) * 128 + g] = wvv;
            p1a[r] += wvv * a1v;
            p2a[r] += wvv * a2v;
        }
    }
#pragma unroll
    for (int s = 1; s < 16; s <<= 1) {
#pragma unroll
        for (int r = 0; r < 4; ++r) {
            p1a[r] += __shfl_xor(p1a[r], s, 64);
            p2a[r] += __shfl_xor(p2a[r], s, 64);
        }
    }
    if (gl == 0) {
#pragma unroll
        for (int r = 0; r < 4; ++r) {
            int row = row0 + wid * 16 + kg * 4 + r;
            s1[row] = p1a[r];
            s2[row] = p2a[r];
        }
    }
}

// ---------------------------------------------------------------------------
// Kernel 2 (verified): stable rank by s2 + exp + threshold count.
// grid = B*32, block = 512. 8 waves each scan 256 keys. Batch = blk&7.
// ---------------------------------------------------------------------------
__global__ __launch_bounds__(512) void k2_rank(
        const float* __restrict__ s2, const float* __restrict__ s1,
        int* __restrict__ idxs, float* __restrict__ ps,
        int* __restrict__ lo_arr) {
    __shared__ __align__(16) float ls[NN];
    __shared__ int part[8][64];
    __shared__ int lpart[8][64];
    __shared__ float wmax[8];
    const int t = threadIdx.x;
    const int blk = blockIdx.x;
    const int b = blk & 7;               // batch -> XCD affinity
    const int seg = blk >> 3;            // 0..31
    const int base = b * NN;
    float4* ls4 = (float4*)ls;
    const float4* g4 = (const float4*)(s2 + base);
    float m;
    {
        float4 v4 = g4[t];
        ls4[t] = v4;
        m = fmaxf(fmaxf(v4.x, v4.y), fmaxf(v4.z, v4.w));
    }
#pragma unroll
    for (int s = 1; s < 64; s <<= 1) m = fmaxf(m, __shfl_xor(m, s, 64));
    if ((t & 63) == 0) wmax[t >> 6] = m;
    __syncthreads();
    float M = wmax[0];
#pragma unroll
    for (int i = 1; i < 8; ++i) M = fmaxf(M, wmax[i]);
    const int jj = t & 63;
    const int w  = t >> 6;
    const int j  = seg * 64 + jj;
    const float v = ls[j];
    const float s1v = s1[base + j];
    int rank = 0, cnt = 0;
#pragma unroll 8
    for (int q = 0; q < 64; ++q) {
        float4 kv = ls4[w * 64 + q];
        int kg = w * 256 + q * 4;
        rank += (kv.x < v) | ((kv.x == v) & (kg + 0 < j));
        rank += (kv.y < v) | ((kv.y == v) & (kg + 1 < j));
        rank += (kv.z < v) | ((kv.z == v) & (kg + 2 < j));
        rank += (kv.w < v) | ((kv.w == v) & (kg + 3 < j));
        cnt += (s1v + kv.x <= 0.f);
        cnt += (s1v + kv.y <= 0.f);
        cnt += (s1v + kv.z <= 0.f);
        cnt += (s1v + kv.w <= 0.f);
    }
    part[w][jj] = rank;
    lpart[w][jj] = cnt;
    __syncthreads();
    if (t < 64) {
        int r = 0, lo = 0;
#pragma unroll
        for (int ww = 0; ww < 8; ++ww) {
            r  += part[ww][t];
            lo += lpart[ww][t];
        }
        int jg = seg * 64 + t;
        float vv = ls[jg];
        idxs[base + r] = jg;
        ps[base + r] = expf(vv - M);
        lo_arr[base + jg] = lo;
    }
}

// ---------------------------------------------------------------------------
// Kernel 34 (merged k3+k4, round-5 logic + XCD affinity): grid = B*32 x 512.
// Each block recomputes its batch's 128 chunk totals (32x redundant gather —
// now L2-local: the whole batch working set lives in THIS XCD's L2).
// Summation orders preserved from the verified round-4/5 pipeline.
// ---------------------------------------------------------------------------
__global__ __launch_bounds__(512) void k34(
        const float* __restrict__ Wh, const int* __restrict__ idxs,
        const float* __restrict__ ps, const int* __restrict__ lo_arr,
        float* __restrict__ out) {
    __shared__ __align__(16) float cs[CH][132];   // 67.6 KB chunk totals -> suffix
    __shared__ float lp[CH];                      // chunk p totals -> suffix
    __shared__ float mvp[8][128];
    __shared__ float mv[128];
    __shared__ float segt[4][128];
    __shared__ __align__(16) int   lidx[NN];      // 8 KB staged idxs
    __shared__ __align__(16) float lps[NN];       // 8 KB staged ps
    const int tid = threadIdx.x;
    const int blk = blockIdx.x;
    const int b = blk & 7;               // batch -> XCD affinity
    const int seg = blk >> 3;            // 0..31 (row group)
    const int base = b * NN;

    // ---- stage idxs/ps for the batch (coalesced, 512 x 16B) ----
    *(int4*)&lidx[tid * 4]  = ((const int4*)(idxs + base))[tid];
    *(float4*)&lps[tid * 4] = ((const float4*)(ps + base))[tid];
    __syncthreads();

    // ---- step 1: chunk totals. wave w owns chunks w*16..w*16+16. ----
    {
        const int lane = tid & 63;
        const int w = tid >> 6;
        const int f2 = lane * 2;
        float ux = 0.f, uy = 0.f;            // unweighted sum (mean)
#pragma unroll 2
        for (int cc = 0; cc < 16; ++cc) {
            const int c = w * 16 + cc;
            float ax = 0.f, ay = 0.f, pacc = 0.f;
#pragma unroll
            for (int t = CHSZ - 1; t >= 0; --t) {     // descending == k3 order
                const int r = c * CHSZ + t;
                const int j = lidx[r];                // LDS broadcast
                const float pv = lps[r];
                float2 wv = *(const float2*)&Wh[(base + j) * 128 + f2];
                ax += pv * wv.x;
                ay += pv * wv.y;
                ux += wv.x;
                uy += wv.y;
                pacc += pv;
            }
            cs[c][f2] = ax;
            cs[c][f2 + 1] = ay;
            if (lane == 0) lp[c] = pacc;
        }
        mvp[w][f2] = ux;
        mvp[w][f2 + 1] = uy;
    }
    __syncthreads();

    // ---- step 2: suffix scans (register-serial 32 / thread + seg offsets) ----
    const int q = tid >> 7;              // 0..3, owns chunks q*32..+32
    const int f = tid & 127;
    float suf[32];
    {
        float acc = 0.f;
#pragma unroll
        for (int i = 31; i >= 0; --i) {
            acc += cs[q * 32 + i][f];
            suf[i] = acc;
        }
        segt[q][f] = acc;
    }
    // lp suffix: wave 0, 2 elems/lane (verified shuffle logic)
    if (tid < 64) {
        float p0 = lp[tid * 2];
        float p1v = lp[tid * 2 + 1];
        float T = p0 + p1v;
#pragma unroll
        for (int s = 1; s < 64; s <<= 1) {
            float t2 = __shfl_down(T, s, 64);
            if (tid + s < 64) T += t2;
        }
        float E = __shfl_down(T, 1, 64);
        if (tid == 63) E = 0.f;
        lp[tid * 2]     = p0 + p1v + E;
        lp[tid * 2 + 1] = p1v + E;
    }
    if (tid < 128) {
        float s = 0.f;
#pragma unroll
        for (int ww = 0; ww < 8; ++ww) s += mvp[ww][tid];
        mv[tid] = s * (1.f / (float)NN);
    }
    __syncthreads();                     // segt visible
    {
        float off = 0.f;
#pragma unroll
        for (int qq = 1; qq < 4; ++qq)
            if (q + qq < 4) off += segt[q + qq][f];
#pragma unroll
        for (int i = 0; i < 32; ++i)
            cs[q * 32 + i][f] = suf[i] + off;   // own cells only
    }
    __syncthreads();
    // cs[c][f] = inclusive suffix; exclusive at c is cs[c+1] (0 if c==127).
    // lp[c]   = inclusive suffix; exclusive at c is lp[c+1].

    // ---- step 3: combine. 64 rows/block via 4 passes of 16 rows. ----
#pragma unroll
    for (int pass = 0; pass < 4; ++pass) {
        const int rowg = base + seg * 64 + pass * 16 + (tid >> 5);
        const int fq = (tid & 31) * 4;
        const int lo = lo_arr[rowg];
        float4 v;
        if (lo == NN) {
            v = make_float4(mv[fq], mv[fq + 1], mv[fq + 2], mv[fq + 3]);
        } else {
            const int c = lo >> 4;       // / CHSZ
            float4 pp = make_float4(0.f, 0.f, 0.f, 0.f);
            float den_p = 0.f;
            // within-chunk suffix at lo: descending r == k3's partial order
            for (int r = c * CHSZ + CHSZ - 1; r >= lo; --r) {
                const int j = lidx[r];
                const float pv = lps[r];
                float4 wv = *(const float4*)&Wh[(base + j) * 128 + fq];
                pp.x += pv * wv.x;
                pp.y += pv * wv.y;
                pp.z += pv * wv.z;
                pp.w += pv * wv.w;
                den_p += pv;
            }
            float4 csv = make_float4(0.f, 0.f, 0.f, 0.f);
            float lpE = 0.f;
            if (c < CH - 1) {
                csv = *(const float4*)&cs[c + 1][fq];
                lpE = lp[c + 1];
            }
            const float den = den_p + lpE;
            v.x = (pp.x + csv.x) / den;
            v.y = (pp.y + csv.y) / den;
            v.z = (pp.z + csv.z) / den;
            v.w = (pp.w + csv.w) / den;
        }
        v.x = (v.x > 0.f) ? v.x : expm1f(v.x);
        v.y = (v.y > 0.f) ? v.y : expm1f(v.y);
        v.z = (v.z > 0.f) ? v.z : expm1f(v.z);
        v.w = (v.w > 0.f) ? v.w : expm1f(v.w);
        *(float4*)&out[rowg * 128 + fq] = v;
    }
}

// ---------------------------------------------------------------------------
extern "C" void kernel_launch(void* const* d_in, const int* in_sizes, int n_in,
                              void* d_out, int out_size, void* d_ws, size_t ws_size,
                              hipStream_t stream) {
    (void)in_sizes; (void)n_in; (void)out_size; (void)ws_size;
    const float* h = (const float*)d_in[0];
    const float* W = (const float*)d_in[1];
    const float* a = (const float*)d_in[2];
    // d_in[3]=A1, d_in[4]=A2: dead code in the reference -> never read.
    float* out = (float*)d_out;

    float* Wh     = (float*)d_ws;            // B*N*F = 2,097,152
    float* s1     = Wh + 2097152;            // 16384
    float* s2     = s1 + 16384;
    float* ps     = s2 + 16384;              // 16384
    int*   idxs   = (int*)(ps + 16384);      // 16384 ints
    int*   lo_arr = idxs + 16384;            // 16384 ints

    k1_wh<<<BB * NN / 64, 256, 0, stream>>>(h, W, a, Wh, s1, s2);
    k2_rank<<<BB * 32, 512, 0, stream>>>(s2, s1, idxs, ps, lo_arr);
    k34<<<BB * 32, 512, 0, stream>>>(Wh, idxs, ps, lo_arr, out);
}

// Round 8
// 176.458 us; speedup vs baseline: 1.0946x; 1.0478x over previous
//
#include <hip/hip_runtime.h>
#include <math.h>

#define BB 8
#define NN 2048
#define FF 128
#define CH 128        // chunks per batch
#define CHSZ 16       // NN / CH

typedef __attribute__((ext_vector_type(8))) short short8;
typedef __attribute__((ext_vector_type(4))) float f32x4;

__device__ __forceinline__ ushort f2bf(float x) {
    uint u = __float_as_uint(x);
    uint r = (u + 0x7FFFu + ((u >> 16) & 1u)) >> 16;   // round-nearest-even
    return (ushort)r;
}
__device__ __forceinline__ float bf2f(ushort x) {
    return __uint_as_float(((uint)x) << 16);
}

// ---------------------------------------------------------------------------
// XCD affinity (verified round 7): batch = blk&7 pins each batch's blocks and
// its ~1.2 MB working set to one XCD L2 across all kernels. Perf-only.
// ---------------------------------------------------------------------------

// ---------------------------------------------------------------------------
// Kernel 1 (MFMA, verified rounds 4/7): Wh = h @ W^T via bf16 hi/lo split.
// ---------------------------------------------------------------------------
__global__ __launch_bounds__(256) void k1_wh(
        const float* __restrict__ h, const float* __restrict__ W,
        const float* __restrict__ a, float* __restrict__ Wh,
        float* __restrict__ s1, float* __restrict__ s2) {
    __shared__ __align__(16) ushort Whi[128][136];
    __shared__ __align__(16) ushort Wlo[128][136];
    __shared__ __align__(16) ushort hhi[64][136];
    __shared__ __align__(16) ushort hlo[64][136];
    const int tid = threadIdx.x;
    const int blk = blockIdx.x;
    const int bb = blk & 7;              // batch -> XCD affinity
    const int w8 = blk >> 3;             // 0..31 within batch
    const int row0 = (bb * 32 + w8) * 64;

    for (int i = tid; i < 4096; i += 256) {
        int g = i >> 5, k4 = (i & 31) * 4;
        float4 wv = *(const float4*)&W[g * 128 + k4];
        ushort h0 = f2bf(wv.x), h1 = f2bf(wv.y), h2 = f2bf(wv.z), h3 = f2bf(wv.w);
        ushort l0 = f2bf(wv.x - bf2f(h0)), l1 = f2bf(wv.y - bf2f(h1));
        ushort l2 = f2bf(wv.z - bf2f(h2)), l3 = f2bf(wv.w - bf2f(h3));
        uint2 hw, lw;
        hw.x = (uint)h0 | ((uint)h1 << 16); hw.y = (uint)h2 | ((uint)h3 << 16);
        lw.x = (uint)l0 | ((uint)l1 << 16); lw.y = (uint)l2 | ((uint)l3 << 16);
        *(uint2*)&Whi[g][k4] = hw;
        *(uint2*)&Wlo[g][k4] = lw;
    }
    for (int i = tid; i < 2048; i += 256) {
        int r = i >> 5, k4 = (i & 31) * 4;
        float4 hv = *(const float4*)&h[(row0 + r) * 128 + k4];
        ushort h0 = f2bf(hv.x), h1 = f2bf(hv.y), h2 = f2bf(hv.z), h3 = f2bf(hv.w);
        ushort l0 = f2bf(hv.x - bf2f(h0)), l1 = f2bf(hv.y - bf2f(h1));
        ushort l2 = f2bf(hv.z - bf2f(h2)), l3 = f2bf(hv.w - bf2f(h3));
        uint2 hw, lw;
        hw.x = (uint)h0 | ((uint)h1 << 16); hw.y = (uint)h2 | ((uint)h3 << 16);
        lw.x = (uint)l0 | ((uint)l1 << 16); lw.y = (uint)l2 | ((uint)l3 << 16);
        *(uint2*)&hhi[r][k4] = hw;
        *(uint2*)&hlo[r][k4] = lw;
    }
    __syncthreads();

    const int lane = tid & 63;
    const int wid = tid >> 6;
    const int gl = lane & 15;
    const int kg = lane >> 4;
    const int lr = wid * 16 + gl;

    f32x4 acc[8];
#pragma unroll
    for (int gt = 0; gt < 8; ++gt) acc[gt] = (f32x4){0.f, 0.f, 0.f, 0.f};

#pragma unroll
    for (int t = 0; t < 4; ++t) {
        const int k0 = t * 32 + kg * 8;
        short8 ah = *(const short8*)&hhi[lr][k0];
        short8 al = *(const short8*)&hlo[lr][k0];
#pragma unroll
        for (int gt = 0; gt < 8; ++gt) {
            const int g = gt * 16 + gl;
            short8 bh = *(const short8*)&Whi[g][k0];
            short8 bl = *(const short8*)&Wlo[g][k0];
            acc[gt] = __builtin_amdgcn_mfma_f32_16x16x32_bf16(ah, bh, acc[gt], 0, 0, 0);
            acc[gt] = __builtin_amdgcn_mfma_f32_16x16x32_bf16(ah, bl, acc[gt], 0, 0, 0);
            acc[gt] = __builtin_amdgcn_mfma_f32_16x16x32_bf16(al, bh, acc[gt], 0, 0, 0);
        }
    }

    float p1a[4] = {0.f, 0.f, 0.f, 0.f}, p2a[4] = {0.f, 0.f, 0.f, 0.f};
#pragma unroll
    for (int gt = 0; gt < 8; ++gt) {
        const int g = gt * 16 + gl;
        const float a1v = a[g];
        const float a2v = a[128 + g];
#pragma unroll
        for (int r = 0; r < 4; ++r) {
            float wvv = acc[gt][r];
            Wh[(row0 + wid * 16 + kg * 4 + r) * 128 + g] = wvv;
            p1a[r] += wvv * a1v;
            p2a[r] += wvv * a2v;
        }
    }
#pragma unroll
    for (int s = 1; s < 16; s <<= 1) {
#pragma unroll
        for (int r = 0; r < 4; ++r) {
            p1a[r] += __shfl_xor(p1a[r], s, 64);
            p2a[r] += __shfl_xor(p2a[r], s, 64);
        }
    }
    if (gl == 0) {
#pragma unroll
        for (int r = 0; r < 4; ++r) {
            int row = row0 + wid * 16 + kg * 4 + r;
            s1[row] = p1a[r];
            s2[row] = p2a[r];
        }
    }
}

// ---------------------------------------------------------------------------
// Kernel 2 (verified rounds 4/7): stable rank by s2 + exp + threshold count.
// ---------------------------------------------------------------------------
__global__ __launch_bounds__(512) void k2_rank(
        const float* __restrict__ s2, const float* __restrict__ s1,
        int* __restrict__ idxs, float* __restrict__ ps,
        int* __restrict__ lo_arr) {
    __shared__ __align__(16) float ls[NN];
    __shared__ int part[8][64];
    __shared__ int lpart[8][64];
    __shared__ float wmax[8];
    const int t = threadIdx.x;
    const int blk = blockIdx.x;
    const int b = blk & 7;               // batch -> XCD affinity
    const int seg = blk >> 3;            // 0..31
    const int base = b * NN;
    float4* ls4 = (float4*)ls;
    const float4* g4 = (const float4*)(s2 + base);
    float m;
    {
        float4 v4 = g4[t];
        ls4[t] = v4;
        m = fmaxf(fmaxf(v4.x, v4.y), fmaxf(v4.z, v4.w));
    }
#pragma unroll
    for (int s = 1; s < 64; s <<= 1) m = fmaxf(m, __shfl_xor(m, s, 64));
    if ((t & 63) == 0) wmax[t >> 6] = m;
    __syncthreads();
    float M = wmax[0];
#pragma unroll
    for (int i = 1; i < 8; ++i) M = fmaxf(M, wmax[i]);
    const int jj = t & 63;
    const int w  = t >> 6;
    const int j  = seg * 64 + jj;
    const float v = ls[j];
    const float s1v = s1[base + j];
    int rank = 0, cnt = 0;
#pragma unroll 8
    for (int q = 0; q < 64; ++q) {
        float4 kv = ls4[w * 64 + q];
        int kg = w * 256 + q * 4;
        rank += (kv.x < v) | ((kv.x == v) & (kg + 0 < j));
        rank += (kv.y < v) | ((kv.y == v) & (kg + 1 < j));
        rank += (kv.z < v) | ((kv.z == v) & (kg + 2 < j));
        rank += (kv.w < v) | ((kv.w == v) & (kg + 3 < j));
        cnt += (s1v + kv.x <= 0.f);
        cnt += (s1v + kv.y <= 0.f);
        cnt += (s1v + kv.z <= 0.f);
        cnt += (s1v + kv.w <= 0.f);
    }
    part[w][jj] = rank;
    lpart[w][jj] = cnt;
    __syncthreads();
    if (t < 64) {
        int r = 0, lo = 0;
#pragma unroll
        for (int ww = 0; ww < 8; ++ww) {
            r  += part[ww][t];
            lo += lpart[ww][t];
        }
        int jg = seg * 64 + t;
        float vv = ls[jg];
        idxs[base + r] = jg;
        ps[base + r] = expf(vv - M);
        lo_arr[base + jg] = lo;
    }
}

// ---------------------------------------------------------------------------
// Kernel 3c (= verified k3 minus partial/psuf): chunk totals only, computed
// once per chunk (no redundancy). grid = B*CH, 128 thr, batch = blk&7.
// Same descending accumulation order as verified k3.
// ---------------------------------------------------------------------------
__global__ __launch_bounds__(128) void k3c(
        const float* __restrict__ Wh, const int* __restrict__ idxs,
        const float* __restrict__ ps,
        float* __restrict__ chunktot, float* __restrict__ chunku,
        float* __restrict__ chunkp) {
    const int blk = blockIdx.x;
    const int b = blk & 7;               // batch -> XCD affinity
    const int c = blk >> 3;              // 0..127
    const int base = b * NN;
    const int f = threadIdx.x;
    float acc = 0.f, accu = 0.f, pacc = 0.f;
#pragma unroll
    for (int tt = CHSZ - 1; tt >= 0; --tt) {
        int r = c * CHSZ + tt;
        int jj = idxs[base + r];
        float pv = ps[base + r];
        float w = Wh[(base + jj) * 128 + f];
        acc += pv * w;
        accu += w;
        pacc += pv;
    }
    chunktot[(b * CH + c) * 128 + f] = acc;
    chunku[(b * CH + c) * 128 + f] = accu;
    if (f == 0) chunkp[b * CH + c] = pacc;
}

// ---------------------------------------------------------------------------
// Kernel 4f: stage chunk totals (round-4-verified structure) + register-
// serial suffix scan (round-4-verified) + recompute-combine (round-5/7-
// verified): pp/den_p re-gathered from L2-hot Wh (<=16 rows per output row).
// grid = B*32 x 512 thr, batch = blk&7.
// ---------------------------------------------------------------------------
__global__ __launch_bounds__(512) void k4f(
        const float* __restrict__ chunktot, const float* __restrict__ chunku,
        const float* __restrict__ chunkp,
        const int* __restrict__ idxs, const float* __restrict__ ps,
        const int* __restrict__ lo_arr, const float* __restrict__ Wh,
        float* __restrict__ out) {
    __shared__ __align__(16) float cs[CH][132];   // 67.6 KB
    __shared__ float lp[CH];
    __shared__ float mvp[4][128];
    __shared__ float mv[128];
    __shared__ float segt[4][128];
    __shared__ __align__(16) int   lidx[NN];      // 8 KB
    __shared__ __align__(16) float lps[NN];       // 8 KB
    const int tid = threadIdx.x;
    const int blk = blockIdx.x;
    const int b = blk & 7;               // batch -> XCD affinity
    const int seg = blk >> 3;            // 0..31 (row group)
    const int base = b * NN;

    // ---- stage idxs/ps (coalesced, 512 x 16B) ----
    *(int4*)&lidx[tid * 4]  = ((const int4*)(idxs + base))[tid];
    *(float4*)&lps[tid * 4] = ((const float4*)(ps + base))[tid];

    // ---- stage chunktot + chunku partial sums (round-4 verified) ----
    {
        const int f  = tid & 127;
        const int r0 = tid >> 7;         // 0..3
        float su = 0.f;
#pragma unroll 4
        for (int i = 0; i < 32; ++i) {
            int c = r0 + i * 4;
            cs[c][f] = chunktot[(b * CH + c) * 128 + f];
            su += chunku[(b * CH + c) * 128 + f];
        }
        mvp[r0][f] = su;
        if (tid < CH) lp[tid] = chunkp[b * CH + tid];
    }
    __syncthreads();
    if (tid < 128)
        mv[tid] = (mvp[0][tid] + mvp[1][tid] + mvp[2][tid] + mvp[3][tid])
                  * (1.f / (float)NN);

    // ---- suffix scans: register-serial 32/thread + seg offsets (verified) ----
    const int q = tid >> 7;              // 0..3, owns chunks q*32..+32
    const int f = tid & 127;
    float suf[32];
    {
        float acc = 0.f;
#pragma unroll
        for (int i = 31; i >= 0; --i) {
            acc += cs[q * 32 + i][f];
            suf[i] = acc;
        }
        segt[q][f] = acc;
    }
    // lp suffix: wave 0, 2 elems/lane (verified shuffle logic)
    if (tid < 64) {
        float p0 = lp[tid * 2];
        float p1v = lp[tid * 2 + 1];
        float T = p0 + p1v;
#pragma unroll
        for (int s = 1; s < 64; s <<= 1) {
            float t2 = __shfl_down(T, s, 64);
            if (tid + s < 64) T += t2;
        }
        float E = __shfl_down(T, 1, 64);
        if (tid == 63) E = 0.f;
        lp[tid * 2]     = p0 + p1v + E;
        lp[tid * 2 + 1] = p1v + E;
    }
    __syncthreads();                     // segt visible
    {
        float off = 0.f;
#pragma unroll
        for (int qq = 1; qq < 4; ++qq)
            if (q + qq < 4) off += segt[q + qq][f];
#pragma unroll
        for (int i = 0; i < 32; ++i)
            cs[q * 32 + i][f] = suf[i] + off;   // own cells only
    }
    __syncthreads();
    // cs[c][f] = inclusive suffix; exclusive at c is cs[c+1] (0 if c==127).
    // lp[c]   = inclusive suffix; exclusive at c is lp[c+1].

    // ---- combine (round-5/7-verified recompute logic) ----
#pragma unroll
    for (int pass = 0; pass < 4; ++pass) {
        const int rowg = base + seg * 64 + pass * 16 + (tid >> 5);
        const int fq = (tid & 31) * 4;
        const int lo = lo_arr[rowg];
        float4 v;
        if (lo == NN) {
            v = make_float4(mv[fq], mv[fq + 1], mv[fq + 2], mv[fq + 3]);
        } else {
            const int c = lo >> 4;       // / CHSZ
            float4 pp = make_float4(0.f, 0.f, 0.f, 0.f);
            float den_p = 0.f;
            // within-chunk suffix at lo: descending r == k3's partial order
            for (int r = c * CHSZ + CHSZ - 1; r >= lo; --r) {
                const int j = lidx[r];
                const float pv = lps[r];
                float4 wv = *(const float4*)&Wh[(base + j) * 128 + fq];
                pp.x += pv * wv.x;
                pp.y += pv * wv.y;
                pp.z += pv * wv.z;
                pp.w += pv * wv.w;
                den_p += pv;
            }
            float4 csv = make_float4(0.f, 0.f, 0.f, 0.f);
            float lpE = 0.f;
            if (c < CH - 1) {
                csv = *(const float4*)&cs[c + 1][fq];
                lpE = lp[c + 1];
            }
            const float den = den_p + lpE;
            v.x = (pp.x + csv.x) / den;
            v.y = (pp.y + csv.y) / den;
            v.z = (pp.z + csv.z) / den;
            v.w = (pp.w + csv.w) / den;
        }
        v.x = (v.x > 0.f) ? v.x : expm1f(v.x);
        v.y = (v.y > 0.f) ? v.y : expm1f(v.y);
        v.z = (v.z > 0.f) ? v.z : expm1f(v.z);
        v.w = (v.w > 0.f) ? v.w : expm1f(v.w);
        *(float4*)&out[rowg * 128 + fq] = v;
    }
}

// ---------------------------------------------------------------------------
extern "C" void kernel_launch(void* const* d_in, const int* in_sizes, int n_in,
                              void* d_out, int out_size, void* d_ws, size_t ws_size,
                              hipStream_t stream) {
    (void)in_sizes; (void)n_in; (void)out_size; (void)ws_size;
    const float* h = (const float*)d_in[0];
    const float* W = (const float*)d_in[1];
    const float* a = (const float*)d_in[2];
    // d_in[3]=A1, d_in[4]=A2: dead code in the reference -> never read.
    float* out = (float*)d_out;

    float* Wh       = (float*)d_ws;            // B*N*F = 2,097,152
    float* s1       = Wh + 2097152;            // 16384
    float* s2       = s1 + 16384;
    float* ps       = s2 + 16384;              // 16384
    int*   idxs     = (int*)(ps + 16384);      // 16384 ints
    int*   lo_arr   = idxs + 16384;            // 16384 ints
    float* chunktot = (float*)(lo_arr + 16384);// B*CH*F = 131072
    float* chunku   = chunktot + 131072;
    float* chunkp   = chunku + 131072;         // B*CH = 1024

    k1_wh<<<BB * NN / 64, 256, 0, stream>>>(h, W, a, Wh, s1, s2);
    k2_rank<<<BB * 32, 512, 0, stream>>>(s2, s1, idxs, ps, lo_arr);
    k3c<<<BB * CH, 128, 0, stream>>>(Wh, idxs, ps, chunktot, chunku, chunkp);
    k4f<<<BB * 32, 512, 0, stream>>>(chunktot, chunku, chunkp,
                                     idxs, ps, lo_arr, Wh, out);
}

// Round 10
// 169.497 us; speedup vs baseline: 1.1395x; 1.0411x over previous
//
#include <hip/hip_runtime.h>
#include <math.h>

#define BB 8
#define NN 2048
#define FF 128
#define CH 128        // chunks per batch
#define CHSZ 16       // NN / CH

typedef __attribute__((ext_vector_type(8))) short short8;
typedef __attribute__((ext_vector_type(4))) float f32x4;

__device__ __forceinline__ ushort f2bf(float x) {
    uint u = __float_as_uint(x);
    uint r = (u + 0x7FFFu + ((u >> 16) & 1u)) >> 16;   // round-nearest-even
    return (ushort)r;
}
__device__ __forceinline__ float bf2f(ushort x) {
    return __uint_as_float(((uint)x) << 16);
}

// ---------------------------------------------------------------------------
// Structure = round-4 pipeline (best measured: 170 µs) + XCD affinity
// (batch = blk&7, verified −8 µs on the r5->r7 A/B). All FP summation
// orders bit-identical to round 4 (absmax 0.0078125).
// ---------------------------------------------------------------------------

// ---------------------------------------------------------------------------
// Kernel 1 (MFMA, verified r4/r7/r8): Wh = h @ W^T via bf16 hi/lo split.
// ---------------------------------------------------------------------------
__global__ __launch_bounds__(256) void k1_wh(
        const float* __restrict__ h, const float* __restrict__ W,
        const float* __restrict__ a, float* __restrict__ Wh,
        float* __restrict__ s1, float* __restrict__ s2) {
    __shared__ __align__(16) ushort Whi[128][136];
    __shared__ __align__(16) ushort Wlo[128][136];
    __shared__ __align__(16) ushort hhi[64][136];
    __shared__ __align__(16) ushort hlo[64][136];
    const int tid = threadIdx.x;
    const int blk = blockIdx.x;
    const int bb = blk & 7;              // batch -> XCD affinity
    const int w8 = blk >> 3;             // 0..31 within batch
    const int row0 = (bb * 32 + w8) * 64;

    for (int i = tid; i < 4096; i += 256) {
        int g = i >> 5, k4 = (i & 31) * 4;
        float4 wv = *(const float4*)&W[g * 128 + k4];
        ushort h0 = f2bf(wv.x), h1 = f2bf(wv.y), h2 = f2bf(wv.z), h3 = f2bf(wv.w);
        ushort l0 = f2bf(wv.x - bf2f(h0)), l1 = f2bf(wv.y - bf2f(h1));
        ushort l2 = f2bf(wv.z - bf2f(h2)), l3 = f2bf(wv.w - bf2f(h3));
        uint2 hw, lw;
        hw.x = (uint)h0 | ((uint)h1 << 16); hw.y = (uint)h2 | ((uint)h3 << 16);
        lw.x = (uint)l0 | ((uint)l1 << 16); lw.y = (uint)l2 | ((uint)l3 << 16);
        *(uint2*)&Whi[g][k4] = hw;
        *(uint2*)&Wlo[g][k4] = lw;
    }
    for (int i = tid; i < 2048; i += 256) {
        int r = i >> 5, k4 = (i & 31) * 4;
        float4 hv = *(const float4*)&h[(row0 + r) * 128 + k4];
        ushort h0 = f2bf(hv.x), h1 = f2bf(hv.y), h2 = f2bf(hv.z), h3 = f2bf(hv.w);
        ushort l0 = f2bf(hv.x - bf2f(h0)), l1 = f2bf(hv.y - bf2f(h1));
        ushort l2 = f2bf(hv.z - bf2f(h2)), l3 = f2bf(hv.w - bf2f(h3));
        uint2 hw, lw;
        hw.x = (uint)h0 | ((uint)h1 << 16); hw.y = (uint)h2 | ((uint)h3 << 16);
        lw.x = (uint)l0 | ((uint)l1 << 16); lw.y = (uint)l2 | ((uint)l3 << 16);
        *(uint2*)&hhi[r][k4] = hw;
        *(uint2*)&hlo[r][k4] = lw;
    }
    __syncthreads();

    const int lane = tid & 63;
    const int wid = tid >> 6;
    const int gl = lane & 15;
    const int kg = lane >> 4;
    const int lr = wid * 16 + gl;

    f32x4 acc[8];
#pragma unroll
    for (int gt = 0; gt < 8; ++gt) acc[gt] = (f32x4){0.f, 0.f, 0.f, 0.f};

#pragma unroll
    for (int t = 0; t < 4; ++t) {
        const int k0 = t * 32 + kg * 8;
        short8 ah = *(const short8*)&hhi[lr][k0];
        short8 al = *(const short8*)&hlo[lr][k0];
#pragma unroll
        for (int gt = 0; gt < 8; ++gt) {
            const int g = gt * 16 + gl;
            short8 bh = *(const short8*)&Whi[g][k0];
            short8 bl = *(const short8*)&Wlo[g][k0];
            acc[gt] = __builtin_amdgcn_mfma_f32_16x16x32_bf16(ah, bh, acc[gt], 0, 0, 0);
            acc[gt] = __builtin_amdgcn_mfma_f32_16x16x32_bf16(ah, bl, acc[gt], 0, 0, 0);
            acc[gt] = __builtin_amdgcn_mfma_f32_16x16x32_bf16(al, bh, acc[gt], 0, 0, 0);
        }
    }

    float p1a[4] = {0.f, 0.f, 0.f, 0.f}, p2a[4] = {0.f, 0.f, 0.f, 0.f};
#pragma unroll
    for (int gt = 0; gt < 8; ++gt) {
        const int g = gt * 16 + gl;
        const float a1v = a[g];
        const float a2v = a[128 + g];
#pragma unroll
        for (int r = 0; r < 4; ++r) {
            float wvv = acc[gt][r];
            Wh[(row0 + wid * 16 + kg * 4 + r) * 128 + g] = wvv;
            p1a[r] += wvv * a1v;
            p2a[r] += wvv * a2v;
        }
    }
#pragma unroll
    for (int s = 1; s < 16; s <<= 1) {
#pragma unroll
        for (int r = 0; r < 4; ++r) {
            p1a[r] += __shfl_xor(p1a[r], s, 64);
            p2a[r] += __shfl_xor(p2a[r], s, 64);
        }
    }
    if (gl == 0) {
#pragma unroll
        for (int r = 0; r < 4; ++r) {
            int row = row0 + wid * 16 + kg * 4 + r;
            s1[row] = p1a[r];
            s2[row] = p2a[r];
        }
    }
}

// ---------------------------------------------------------------------------
// Kernel 2 (verified r4/r7/r8): stable rank by s2 + exp + threshold count.
// ---------------------------------------------------------------------------
__global__ __launch_bounds__(512) void k2_rank(
        const float* __restrict__ s2, const float* __restrict__ s1,
        int* __restrict__ idxs, float* __restrict__ ps,
        int* __restrict__ lo_arr) {
    __shared__ __align__(16) float ls[NN];
    __shared__ int part[8][64];
    __shared__ int lpart[8][64];
    __shared__ float wmax[8];
    const int t = threadIdx.x;
    const int blk = blockIdx.x;
    const int b = blk & 7;               // batch -> XCD affinity
    const int seg = blk >> 3;            // 0..31
    const int base = b * NN;
    float4* ls4 = (float4*)ls;
    const float4* g4 = (const float4*)(s2 + base);
    float m;
    {
        float4 v4 = g4[t];
        ls4[t] = v4;
        m = fmaxf(fmaxf(v4.x, v4.y), fmaxf(v4.z, v4.w));
    }
#pragma unroll
    for (int s = 1; s < 64; s <<= 1) m = fmaxf(m, __shfl_xor(m, s, 64));
    if ((t & 63) == 0) wmax[t >> 6] = m;
    __syncthreads();
    float M = wmax[0];
#pragma unroll
    for (int i = 1; i < 8; ++i) M = fmaxf(M, wmax[i]);
    const int jj = t & 63;
    const int w  = t >> 6;
    const int j  = seg * 64 + jj;
    const float v = ls[j];
    const float s1v = s1[base + j];
    int rank = 0, cnt = 0;
#pragma unroll 8
    for (int q = 0; q < 64; ++q) {
        float4 kv = ls4[w * 64 + q];
        int kg = w * 256 + q * 4;
        rank += (kv.x < v) | ((kv.x == v) & (kg + 0 < j));
        rank += (kv.y < v) | ((kv.y == v) & (kg + 1 < j));
        rank += (kv.z < v) | ((kv.z == v) & (kg + 2 < j));
        rank += (kv.w < v) | ((kv.w == v) & (kg + 3 < j));
        cnt += (s1v + kv.x <= 0.f);
        cnt += (s1v + kv.y <= 0.f);
        cnt += (s1v + kv.z <= 0.f);
        cnt += (s1v + kv.w <= 0.f);
    }
    part[w][jj] = rank;
    lpart[w][jj] = cnt;
    __syncthreads();
    if (t < 64) {
        int r = 0, lo = 0;
#pragma unroll
        for (int ww = 0; ww < 8; ++ww) {
            r  += part[ww][t];
            lo += lpart[ww][t];
        }
        int jg = seg * 64 + t;
        float vv = ls[jg];
        idxs[base + r] = jg;
        ps[base + r] = expf(vv - M);
        lo_arr[base + jg] = lo;
    }
}

// ---------------------------------------------------------------------------
// Kernel 3 (round-4 full version + affinity): within-chunk inclusive suffix
// of p*Wh (-> partial), p (-> psuf, f==0), plus chunk totals/unweighted sums.
// grid = B*CH, 128 thr. batch = blk&7, c = blk>>3. Descending order.
// ---------------------------------------------------------------------------
__global__ __launch_bounds__(128) void k3_scan(
        const float* __restrict__ Wh, const int* __restrict__ idxs,
        const float* __restrict__ ps,
        float* __restrict__ partial, float* __restrict__ psuf,
        float* __restrict__ chunktot, float* __restrict__ chunku,
        float* __restrict__ chunkp) {
    const int blk = blockIdx.x;
    const int b = blk & 7;               // batch -> XCD affinity
    const int c = blk >> 3;              // 0..127
    const int base = b * NN;
    const int f = threadIdx.x;
    float acc = 0.f, accu = 0.f, pacc = 0.f;
#pragma unroll
    for (int tt = CHSZ - 1; tt >= 0; --tt) {
        int r = c * CHSZ + tt;
        int jj = idxs[base + r];
        float pv = ps[base + r];
        float w = Wh[(base + jj) * 128 + f];
        acc += pv * w;
        accu += w;
        pacc += pv;
        partial[(base + r) * 128 + f] = acc;
        if (f == 0) psuf[base + r] = pacc;
    }
    chunktot[(b * CH + c) * 128 + f] = acc;
    chunku[(b * CH + c) * 128 + f] = accu;
    if (f == 0) chunkp[b * CH + c] = pacc;
}

// ---------------------------------------------------------------------------
// Kernel 4 (round-4 k4_merged + affinity): grid = B*32 x 512 thr.
//   Phase A: per-thread serial suffix over 32 chunktot values (registers,
//            coalesced global reads); chunku summed for the mean.
//   lp suffix: wave 0 shuffle scan (2 elems/lane).
//   Phase C: add 3 upper-segment totals, single LDS write per c.
//   Combine: partial[lo] + cs[c+1] (LDS), den = psuf[lo] + lp[c+1]; ELU.
// All orders bit-identical to round 4.
// ---------------------------------------------------------------------------
__global__ __launch_bounds__(512) void k4_merged(
        const float* __restrict__ chunktot, const float* __restrict__ chunku,
        const float* __restrict__ chunkp,
        const int* __restrict__ lo_arr, const float* __restrict__ psuf,
        const float* __restrict__ partial, float* __restrict__ out) {
    __shared__ __align__(16) float cs[CH][132];   // 67.6 KB, float4-aligned rows
    __shared__ float segt[4][128];
    __shared__ float mvp[4][128];
    __shared__ float mv[128];
    __shared__ float lp[CH];
    const int tid = threadIdx.x;
    const int blk = blockIdx.x;
    const int b = blk & 7;               // batch -> XCD affinity
    const int seg = blk >> 3;            // 0..31 (row group)
    const int base = b * NN;
    const int f = tid & 127;
    const int q = tid >> 7;              // segment 0..3

    // ---- Phase A: per-thread serial suffix over 32 c's (registers) ----
    float suf[32];
    float acc = 0.f, su = 0.f;
#pragma unroll
    for (int i = 31; i >= 0; --i) {
        int c = q * 32 + i;
        acc += chunktot[(b * CH + c) * 128 + f];
        su  += chunku[(b * CH + c) * 128 + f];
        suf[i] = acc;
    }
    segt[q][f] = acc;
    mvp[q][f] = su;

    // ---- lp (chunkp) suffix scan: wave 0, 2 elems per lane ----
    if (tid < 64) {
        float p0 = chunkp[b * CH + tid * 2];
        float p1v = chunkp[b * CH + tid * 2 + 1];
        float T = p0 + p1v;
#pragma unroll
        for (int s = 1; s < 64; s <<= 1) {
            float t2 = __shfl_down(T, s, 64);
            if (tid + s < 64) T += t2;
        }
        float E = __shfl_down(T, 1, 64);   // exclusive pair-suffix
        if (tid == 63) E = 0.f;
        lp[tid * 2]     = p0 + p1v + E;
        lp[tid * 2 + 1] = p1v + E;
    }
    __syncthreads();

    // ---- Phase C: segment offsets, write suffix to LDS, mean ----
    float off = 0.f;
#pragma unroll
    for (int qq = 1; qq < 4; ++qq)
        if (q + qq < 4) off += segt[q + qq][f];
#pragma unroll
    for (int i = 0; i < 32; ++i)
        cs[q * 32 + i][f] = suf[i] + off;
    if (tid < 128)
        mv[tid] = (mvp[0][tid] + mvp[1][tid] + mvp[2][tid] + mvp[3][tid])
                  * (1.f / (float)NN);
    __syncthreads();
    // cs[c][f] = inclusive suffix; exclusive at c is cs[c+1] (0 if c==127).

    // ---- combine (round-4-verified logic, LDS-resident suffixes) ----
#pragma unroll
    for (int pass = 0; pass < 4; ++pass) {
        const int rowg = base + seg * 64 + pass * 16 + (tid >> 5);
        const int fq = (tid & 31) * 4;
        const int lo = lo_arr[rowg];
        float4 v;
        if (lo == NN) {
            v = make_float4(mv[fq], mv[fq + 1], mv[fq + 2], mv[fq + 3]);
        } else {
            const int c = lo >> 4;       // / CHSZ
            float4 pp = *(const float4*)&partial[(base + lo) * 128 + fq];
            float4 csv = make_float4(0.f, 0.f, 0.f, 0.f);
            float lps = 0.f;
            if (c < CH - 1) {
                csv = *(const float4*)&cs[c + 1][fq];
                lps = lp[c + 1];
            }
            float den = psuf[base + lo] + lps;
            v.x = (pp.x + csv.x) / den;
            v.y = (pp.y + csv.y) / den;
            v.z = (pp.z + csv.z) / den;
            v.w = (pp.w + csv.w) / den;
        }
        v.x = (v.x > 0.f) ? v.x : expm1f(v.x);
        v.y = (v.y > 0.f) ? v.y : expm1f(v.y);
        v.z = (v.z > 0.f) ? v.z : expm1f(v.z);
        v.w = (v.w > 0.f) ? v.w : expm1f(v.w);
        *(float4*)&out[rowg * 128 + fq] = v;
    }
}

// ---------------------------------------------------------------------------
extern "C" void kernel_launch(void* const* d_in, const int* in_sizes, int n_in,
                              void* d_out, int out_size, void* d_ws, size_t ws_size,
                              hipStream_t stream) {
    (void)in_sizes; (void)n_in; (void)out_size; (void)ws_size;
    const float* h = (const float*)d_in[0];
    const float* W = (const float*)d_in[1];
    const float* a = (const float*)d_in[2];
    // d_in[3]=A1, d_in[4]=A2: dead code in the reference -> never read.
    float* out = (float*)d_out;

    float* Wh       = (float*)d_ws;            // B*N*F = 2,097,152
    float* partial  = Wh + 2097152;            // B*N*F = 2,097,152
    float* s1       = partial + 2097152;       // 16384
    float* s2       = s1 + 16384;
    float* ps       = s2 + 16384;              // 16384
    float* psuf     = ps + 16384;              // 16384
    int*   idxs     = (int*)(psuf + 16384);    // 16384 ints
    int*   lo_arr   = idxs + 16384;            // 16384 ints
    float* chunktot = (float*)(lo_arr + 16384);// B*CH*F = 131072
    float* chunku   = chunktot + 131072;
    float* chunkp   = chunku + 131072;         // B*CH = 1024

    k1_wh<<<BB * NN / 64, 256, 0, stream>>>(h, W, a, Wh, s1, s2);
    k2_rank<<<BB * 32, 512, 0, stream>>>(s2, s1, idxs, ps, lo_arr);
    k3_scan<<<BB * CH, 128, 0, stream>>>(Wh, idxs, ps, partial, psuf,
                                         chunktot, chunku, chunkp);
    k4_merged<<<BB * 32, 512, 0, stream>>>(chunktot, chunku, chunkp,
                                           lo_arr, psuf, partial, out);
}